// Round 16
// baseline (192.632 us; speedup 1.0000x reference)
//
#include <hip/hip_runtime.h>
#include <hip/hip_bf16.h>

// B=4, S=2048, D=1024. x:[4,2048,1024] f32; wq/wk/wv:[1024,1024] f32.
// out:[4,2048,1024] f32.
//
// R16 pipeline:
//   scores = x (Wq Wk^T/32) x^T  (Mt precomputed; K-proj eliminated)
//   1. convall: x,wq,wk -> bf16
//   2. wtrans:  wv -> wtv bf16 transposed
//   3. gemm64<0>:  Mt = (wkb @ wqb^T)/32       [1024x1024] bf16 (R14 3-ring)
//   4. gemm_hw<5>: t  = xb @ Mt^T              [8192x1024] bf16, 256 blocks
//   5. gemm_hw<1>: MERGED: 288 live-triangular 128x256 scores (bf16)
//                  + 256 VT blocks = 544
//   6. softmax_wave: row-per-wave register softmax, bf16 in-place
//   7. gemm64<2>:  out = attn @ vt^T (R14 3-ring, equal-K quads)
//
// R16 change (single structural variable): wave tile 64x64 -> 64x128.
// gemm_hw: block 128x256, 4 waves (2m x 2n), each wave acc[4][8] = 32 MFMA
// per BK=32 step (156 cy of MFMA per chain vs 78) — doubles the MFMA-to-
// chain-overhead ratio that has pinned MfmaUtil at ~21% for 8 rounds.
// BK=32 2-buffer (48 KiB), counted vmcnt(6) (6 staging loads/thread/tile,
// outstanding 12 -> retire tile t only), same 0-conflict both-sides XOR
// swizzle, lgkm pin (R12: unpinning was slightly worse), no setprio.

typedef __attribute__((ext_vector_type(8))) short bf16x8;
typedef __attribute__((ext_vector_type(4))) float f32x4;

#define GLOAD_LDS16(g, l)                                                     \
    __builtin_amdgcn_global_load_lds(                                         \
        (const __attribute__((address_space(1))) void*)(g),                   \
        (__attribute__((address_space(3))) void*)(l), 16, 0, 0)

__device__ __forceinline__ short f2bf(float f) {
    union { float f; unsigned u; } v; v.f = f;
    unsigned r = v.u + 0x7FFFu + ((v.u >> 16) & 1u);
    return (short)(r >> 16);
}
__device__ __forceinline__ float bf2f(short h) {
    union { unsigned u; float f; } v;
    v.u = ((unsigned)(unsigned short)h) << 16;
    return v.f;
}

// ------- fused f32->bf16 converts ----------------------------------------
__global__ __launch_bounds__(256) void convall(
    const float* __restrict__ x, const float* __restrict__ wq,
    const float* __restrict__ wk, short* __restrict__ xb,
    short* __restrict__ wqb, short* __restrict__ wkb) {
    int i = blockIdx.x * 256 + threadIdx.x;  // grid 2048
#pragma unroll
    for (int s = 0; s < 5; ++s) {
        int v = i + s * 524288;              // < 2621440
        const float* src;
        short* dst;
        int off;
        if (v < 2097152)      { src = x;  dst = xb;  off = v; }
        else if (v < 2359296) { src = wq; dst = wqb; off = v - 2097152; }
        else                  { src = wk; dst = wkb; off = v - 2359296; }
        float4 w = ((const float4*)src)[off];
        short4 o;
        o.x = f2bf(w.x); o.y = f2bf(w.y); o.z = f2bf(w.z); o.w = f2bf(w.w);
        ((short4*)dst)[off] = o;
    }
}

// ---------------- wv: f32 [k][n] -> bf16 [n][k] ----------------
__global__ __launch_bounds__(256) void wtrans(const float* __restrict__ W,
                                              short* __restrict__ O) {
    int n0 = blockIdx.x * 64, k0 = blockIdx.y * 64;
    __shared__ float tile[64][65];
    int t = threadIdx.x;
#pragma unroll
    for (int i = 0; i < 16; ++i) {
        int idx = t + i * 256;
        int r = idx >> 6, c = idx & 63;
        tile[r][c] = W[(size_t)(k0 + r) * 1024 + n0 + c];
    }
    __syncthreads();
#pragma unroll
    for (int i = 0; i < 16; ++i) {
        int idx = t + i * 256;
        int r = idx >> 6, c = idx & 63;
        O[(size_t)(n0 + r) * 1024 + k0 + c] = f2bf(tile[c][r]);
    }
}

// ------- gemm_hw: 128x256 block, 4 waves of 64x128, BK=32, 2-buffer -------
// MODE 5: t (bf16 out ld 1024), grid 256: m0=(bid>>2)*128, n0=(bid&3)*256
// MODE 1: merged, grid 544: bid<288 scores (triangular 128x256, causal,
//         bf16 out ld 2048); bid>=288 VT (bf16 out [4][1024][2048])
template <int MODE>
__global__ __launch_bounds__(256, 2) void gemm_hw(
    const short* __restrict__ A0, long long sA,
    const short* __restrict__ B0, long long sB,
    void* __restrict__ C0,
    const short* __restrict__ Av, const short* __restrict__ Bv,
    short* __restrict__ Cv) {

    int m0, n0, z = 0;
    const short* Ab;
    const short* Bb;
    bool isVT = false;

    {
        // T1: XCD swizzle (256 and 544 are multiples of 8)
        const int nblk = gridDim.x;
        const int raw = blockIdx.x;
        int bid = (raw & 7) * (nblk >> 3) + (raw >> 3);
        if (MODE == 5) {
            m0 = (bid >> 2) * 128;        // M=8192
            n0 = (bid & 3) * 256;         // N=1024
            Ab = A0; Bb = B0;
        } else {
            if (bid < 288) {              // scores: live triangular blocks
                z = bid / 72;
                int f = bid - z * 72;
                int mt = 0;
                for (; mt < 16; ++mt) {   // wave-uniform small loop
                    int c = (mt >> 1) + 1;
                    if (f < c) break;
                    f -= c;
                }
                m0 = mt * 128;
                n0 = f * 256;             // n0 <= m0+127 guaranteed
                Ab = A0 + (size_t)z * sA;
                Bb = B0 + (size_t)z * sB;
            } else {
                isVT = true;
                int v = bid - 288;        // 0..255
                m0 = (v >> 5) * 128;      // M=1024
                n0 = (v & 31) * 256;      // N=8192
                Ab = Av; Bb = Bv;
            }
        }
    }

    const int tid = threadIdx.x;
    const int lane = tid & 63;
    const int wid = tid >> 6;
    const int wm = wid >> 1, wn = wid & 1;  // 2x2 waves, wave tile 64x128

    // 2-buffer: A[2][128x32] (16 KiB) + B[2][256x32] (32 KiB) = 48 KiB
    __shared__ __align__(16) short As[2][4096];
    __shared__ __align__(16) short Bs[2][8192];

    f32x4 acc[4][8] = {};

    const int nt = 32;   // K=1024, BK=32

    // staging: 4 thr/row x 16B; A 2 passes (+64 rows), B 4 passes (+64).
    // writer pre-swizzle: phys slot (tid&3) holds logical (tid&3)^((row>>1)&3)
    const int srow = tid >> 2;                  // 0..63
    const int sl = (tid & 3) ^ ((tid >> 3) & 3);
    const short* Agp = Ab + (size_t)(m0 + srow) * 1024 + sl * 8;
    const short* Bgp = Bb + (size_t)(n0 + srow) * 1024 + sl * 8;

#define SA(kt, bf)                                                            \
    do {                                                                      \
        const int _k = (kt) << 5;                                             \
        GLOAD_LDS16(Agp + _k,            &As[bf][tid * 8]);                   \
        GLOAD_LDS16(Agp + _k + 65536,    &As[bf][2048 + tid * 8]);            \
    } while (0)
#define SB(kt, bf)                                                            \
    do {                                                                      \
        const int _k = (kt) << 5;                                             \
        GLOAD_LDS16(Bgp + _k,            &Bs[bf][tid * 8]);                   \
        GLOAD_LDS16(Bgp + _k + 65536,    &Bs[bf][2048 + tid * 8]);            \
        GLOAD_LDS16(Bgp + _k + 131072,   &Bs[bf][4096 + tid * 8]);            \
        GLOAD_LDS16(Bgp + _k + 196608,   &Bs[bf][6144 + tid * 8]);            \
    } while (0)

    const int r = lane & 15;
    const int g = lane >> 4;   // logical 16B slot (k-chunk) 0..3

#define LDA4(dst, bf)                                                         \
    _Pragma("unroll") for (int q_ = 0; q_ < 4; ++q_) {                        \
        const int rr = wm * 64 + q_ * 16 + r;                                 \
        dst[q_] = *(const bf16x8*)&As[bf][rr * 32 +                           \
                                          ((g ^ ((rr >> 1) & 3))) * 8];       \
    }
#define LDB8(dst, bf)                                                         \
    _Pragma("unroll") for (int q_ = 0; q_ < 8; ++q_) {                        \
        const int rb = wn * 128 + q_ * 16 + r;                                \
        dst[q_] = *(const bf16x8*)&Bs[bf][rb * 32 +                           \
                                          ((g ^ ((rb >> 1) & 3))) * 8];       \
    }
#define LGKM0()                                                               \
    asm volatile("s_waitcnt lgkmcnt(0)" ::: "memory");                        \
    __builtin_amdgcn_sched_barrier(0)
#define VMC(n) asm volatile("s_waitcnt vmcnt(" #n ")" ::: "memory")
#define BAR() __builtin_amdgcn_s_barrier()

    SA(0, 0); SB(0, 0);

    int buf = 0;
    for (int t = 0; t < nt; ++t) {
        const int nb = buf ^ 1;
        bf16x8 a[4], b[8];
        if (t + 1 < nt) {
            SA(t + 1, nb); SB(t + 1, nb);
            VMC(6);   // outstanding 12: retire tile t's 6, keep t+1's 6
        } else {
            VMC(0);
        }
        BAR();   // tile t visible; reads of nb (iter t-1) retired
        LDA4(a, buf); LDB8(b, buf);
        LGKM0();
#pragma unroll
        for (int mi = 0; mi < 4; ++mi)
#pragma unroll
            for (int ni = 0; ni < 8; ++ni)
                acc[mi][ni] = __builtin_amdgcn_mfma_f32_16x16x32_bf16(
                    a[mi], b[ni], acc[mi][ni], 0, 0, 0);
        BAR();   // all waves done reading buf before iter t+1 restages it
        buf = nb;
    }

    // ---- C epilogue: C/D layout col=lane&15, row=(lane>>4)*4+reg
    const int r4 = (lane >> 4) * 4;
#pragma unroll
    for (int mi = 0; mi < 4; ++mi) {
#pragma unroll
        for (int ni = 0; ni < 8; ++ni) {
            int col = n0 + wn * 128 + ni * 16 + r;
#pragma unroll
            for (int i = 0; i < 4; ++i) {
                int rr = m0 + wm * 64 + mi * 16 + r4 + i;
                float v = acc[mi][ni][i];
                if (MODE == 5) {
                    ((short*)C0)[(size_t)rr * 1024 + col] = f2bf(v);
                } else {
                    if (isVT) {
                        Cv[(size_t)(col >> 11) * 2097152 +
                           (size_t)rr * 2048 + (col & 2047)] = f2bf(v);
                    } else if (col <= rr) {
                        ((short*)C0)[(size_t)z * 4194304 +
                                     (size_t)rr * 2048 + col] = f2bf(v);
                    }
                }
            }
        }
    }
#undef SA
#undef SB
#undef LDA4
#undef LDB8
#undef LGKM0
#undef VMC
#undef BAR
}

// ------- 64x128 NT GEMM, 2 waves, BK=32 3-ring (R14, proven) -------
// MODE 0: Mt (bf16 out ld 1024, *scale), grid 128, XCD swizzle
// MODE 2: PV (f32 out), grid 1024, equal-K quads, Kend=((m0+63)|127)+1
template <int MODE>
__global__ __launch_bounds__(128, 2) void gemm64(
    const short* __restrict__ A0, int lda, long long sA,
    const short* __restrict__ B0, int ldb, long long sB,
    void* __restrict__ C0, float scale) {

    int m0, n0, z = 0;
    const short* Ab;
    const short* Bb;

    if (MODE == 2) {
        int i = blockIdx.x;            // 0..1023
        int j = i & 255;
        int mt = j >> 3;               // 0..31
        z = (j >> 1) & 3;
        m0 = mt * 64;
        n0 = ((j & 1) + (i >> 8) * 2) * 128;
        Ab = A0 + (size_t)z * sA;
        Bb = B0 + (size_t)z * sB;
    } else {
        const int nblk = gridDim.x;    // 128
        const int raw = blockIdx.x;
        int bid = (raw & 7) * (nblk >> 3) + (raw >> 3);
        m0 = (bid >> 3) * 64;
        n0 = (bid & 7) * 128;
        Ab = A0; Bb = B0;
    }

    const int tid = threadIdx.x;       // 0..127
    const int lane = tid & 63;
    const int wn = tid >> 6;

    __shared__ __align__(16) short As[3][2048];
    __shared__ __align__(16) short Bs[3][4096];

    f32x4 acc[4][4] = {};

    const int Kend = (MODE == 2) ? (((m0 + 63) | 127) + 1) : 1024;
    const int nt = Kend >> 5;

    const int srow = tid >> 2;                  // 0..31
    const int sl = (tid & 3) ^ ((tid >> 3) & 3);
    const short* Agp = Ab + (size_t)(m0 + srow) * lda + sl * 8;
    const short* Bgp = Bb + (size_t)(n0 + srow) * ldb + sl * 8;

#define SA6(kt, bf)                                                           \
    do {                                                                      \
        const int _k = (kt) << 5;                                             \
        GLOAD_LDS16(Agp + _k,                    &As[bf][tid * 8]);           \
        GLOAD_LDS16(Agp + _k + (size_t)32 * lda, &As[bf][1024 + tid * 8]);    \
    } while (0)
#define SB6(kt, bf)                                                           \
    do {                                                                      \
        const int _k = (kt) << 5;                                             \
        GLOAD_LDS16(Bgp + _k,                    &Bs[bf][tid * 8]);           \
        GLOAD_LDS16(Bgp + _k + (size_t)32 * ldb, &Bs[bf][1024 + tid * 8]);    \
        GLOAD_LDS16(Bgp + _k + (size_t)64 * ldb, &Bs[bf][2048 + tid * 8]);    \
        GLOAD_LDS16(Bgp + _k + (size_t)96 * ldb, &Bs[bf][3072 + tid * 8]);    \
    } while (0)

    const int r = lane & 15;
    const int g = lane >> 4;

#define LDA4g(dst, bf)                                                        \
    _Pragma("unroll") for (int q_ = 0; q_ < 4; ++q_) {                        \
        const int rr = q_ * 16 + r;                                           \
        dst[q_] = *(const bf16x8*)&As[bf][rr * 32 +                           \
                                          ((g ^ ((rr >> 1) & 3))) * 8];       \
    }
#define LDB4g(dst, bf)                                                        \
    _Pragma("unroll") for (int q_ = 0; q_ < 4; ++q_) {                        \
        const int rb = wn * 64 + q_ * 16 + r;                                 \
        dst[q_] = *(const bf16x8*)&Bs[bf][rb * 32 +                           \
                                          ((g ^ ((rb >> 1) & 3))) * 8];       \
    }
#define LGKM0()                                                               \
    asm volatile("s_waitcnt lgkmcnt(0)" ::: "memory");                        \
    __builtin_amdgcn_sched_barrier(0)
#define VMC(n) asm volatile("s_waitcnt vmcnt(" #n ")" ::: "memory")
#define BAR() __builtin_amdgcn_s_barrier()
#define MF(ar, br)                                                            \
    _Pragma("unroll") for (int mi = 0; mi < 4; ++mi)                          \
        _Pragma("unroll") for (int ni = 0; ni < 4; ++ni)                      \
            acc[mi][ni] = __builtin_amdgcn_mfma_f32_16x16x32_bf16(            \
                ar[mi], br[ni], acc[mi][ni], 0, 0, 0);

    SA6(0, 0); SB6(0, 0);
    SA6(1, 1); SB6(1, 1);

    int bf = 0;
    int bs = 2;
    for (int t = 0; t < nt; ++t) {
        bf16x8 a[4], b[4];
        if (t + 2 < nt) {
            SA6(t + 2, bs); SB6(t + 2, bs);
            VMC(12);
        } else if (t + 1 < nt) {
            VMC(6);
        } else {
            VMC(0);
        }
        BAR();
        LDA4g(a, bf); LDB4g(b, bf);
        LGKM0();
        MF(a, b);
        BAR();
        bf = (bf == 2) ? 0 : bf + 1;
        bs = (bs == 2) ? 0 : bs + 1;
    }

    const int r4 = (lane >> 4) * 4;
#pragma unroll
    for (int mi = 0; mi < 4; ++mi) {
#pragma unroll
        for (int ni = 0; ni < 4; ++ni) {
            int col = n0 + wn * 64 + ni * 16 + r;
#pragma unroll
            for (int i = 0; i < 4; ++i) {
                int rr = m0 + mi * 16 + r4 + i;
                float v = acc[mi][ni][i];
                if (MODE == 0) {
                    ((short*)C0)[(size_t)rr * 1024 + col] = f2bf(v * scale);
                } else {
                    ((float*)C0)[(size_t)z * 2097152 +
                                 (size_t)rr * 1024 + col] = v;
                }
            }
        }
    }
#undef SA6
#undef SB6
#undef LDA4g
#undef LDB4g
#undef LGKM0
#undef VMC
#undef BAR
#undef MF
}

// ------- causal softmax, row per wave, all-register, bf16 in/out -----------
__global__ __launch_bounds__(256) void softmax_wave(short* __restrict__ scores) {
    int row = (blockIdx.x << 2) + (threadIdx.x >> 6);  // 0..8191
    int lane = threadIdx.x & 63;
    int b = row >> 11, i = row & 2047;
    short* srow = scores + ((size_t)(b << 11) + i) * 2048;
    int L = i + 1;
    int Lpad = (i | 127) + 1;

    float vals[32];
    float mx = -1e30f;
#pragma unroll
    for (int s = 0; s < 4; ++s) {
        if (s * 512 < Lpad) {
            int j0 = (s << 9) + (lane << 3);
            bf16x8 h = *(const bf16x8*)&srow[j0];
#pragma unroll
            for (int e = 0; e < 8; ++e) {
                float f = ((j0 + e) < L) ? bf2f(h[e]) : -1e30f;
                vals[s * 8 + e] = f;
                mx = fmaxf(mx, f);
            }
        }
    }
#pragma unroll
    for (int o = 32; o > 0; o >>= 1) mx = fmaxf(mx, __shfl_down(mx, o));
    mx = __shfl(mx, 0);

    float sum = 0.f;
#pragma unroll
    for (int s = 0; s < 4; ++s) {
        if (s * 512 < Lpad) {
#pragma unroll
            for (int e = 0; e < 8; ++e) {
                float ex = __expf(vals[s * 8 + e] - mx);
                vals[s * 8 + e] = ex;
                sum += ex;
            }
        }
    }
#pragma unroll
    for (int o = 32; o > 0; o >>= 1) sum += __shfl_down(sum, o);
    sum = __shfl(sum, 0);
    float rinv = 1.0f / sum;

#pragma unroll
    for (int s = 0; s < 4; ++s) {
        if (s * 512 < Lpad) {
            int j0 = (s << 9) + (lane << 3);
            bf16x8 o8;
#pragma unroll
            for (int e = 0; e < 8; ++e) o8[e] = f2bf(vals[s * 8 + e] * rinv);
            *(bf16x8*)&srow[j0] = o8;
        }
    }
}

extern "C" void kernel_launch(void* const* d_in, const int* in_sizes, int n_in,
                              void* d_out, int out_size, void* d_ws, size_t ws_size,
                              hipStream_t stream) {
    const float* x  = (const float*)d_in[0];
    const float* wq = (const float*)d_in[1];
    const float* wk = (const float*)d_in[2];
    const float* wv = (const float*)d_in[3];
    float* out = (float*)d_out;

    // workspace layout (shorts)
    short* ws16 = (short*)d_ws;
    short* xb  = ws16;                 //  8,388,608
    short* wqb = xb + 8388608;         //  1,048,576
    short* wkb = wqb + 1048576;        //  1,048,576
    short* wtv = wkb + 1048576;        //  1,048,576  Wv^T [n][k]
    short* Mt  = wtv + 1048576;        //  1,048,576  (Wk Wq^T)/32
    short* tb  = Mt + 1048576;         //  8,388,608  t = x M
    short* vt  = tb + 8388608;         //  8,388,608  V^T [4][1024][2048]
    short* scores = vt + 8388608;      // 16,777,216  bf16 [4][2048][2048]

    convall<<<2048, 256, 0, stream>>>(x, wq, wk, xb, wqb, wkb);
    wtrans<<<dim3(16, 16, 1), 256, 0, stream>>>(wv, wtv);
    // Mt[m][n] = sum_e Wk[m][e] Wq[n][e] / 32
    gemm64<0><<<128, 128, 0, stream>>>(
        wkb, 1024, 0LL, wqb, 1024, 0LL, Mt, 0.03125f);
    // t[i][n] = sum_k x[i][k] Mt[n][k]   (gemm_hw, 256 blocks)
    gemm_hw<5><<<256, 256, 0, stream>>>(
        xb, 0LL, Mt, 0LL, tb, nullptr, nullptr, nullptr);
    // merged: scores (288 live triangular 128x256, bf16) + VT (256)
    gemm_hw<1><<<544, 256, 0, stream>>>(
        tb, 2097152LL, xb, 2097152LL, scores, wtv, xb, vt);
    softmax_wave<<<2048, 256, 0, stream>>>(scores);
    // out = attn @ vt^T  (gemm64 3-ring, 1024 blocks, equal-K quads)
    gemm64<2><<<1024, 128, 0, stream>>>(
        scores, 2048, 4194304LL, vt, 2048, 2097152LL, out, 1.0f);
}

// Round 17
// 173.668 us; speedup vs baseline: 1.1092x; 1.1092x over previous
//
#include <hip/hip_runtime.h>
#include <hip/hip_bf16.h>

// B=4, S=2048, D=1024. x:[4,2048,1024] f32; wq/wk/wv:[1024,1024] f32.
// out:[4,2048,1024] f32.
//
// R17 pipeline (= R14; both GEMM cores get fragment-prefetch schedule):
//   scores = x (Wq Wk^T/32) x^T  (Mt precomputed; K-proj eliminated)
//   1. convall: x,wq,wk -> bf16
//   2. wtrans:  wv -> wtv bf16 transposed
//   3. gemm64<0>:  Mt = (wkb @ wqb^T)/32       [1024x1024] bf16
//   4. gemm128<5>: t  = xb @ Mt^T              [8192x1024] bf16
//   5. gemm128<1>: MERGED: 544 live-triangular scores (bf16) + 512 VT
//   6. softmax_wave: row-per-wave register softmax, bf16 in-place
//   7. gemm64<2>:  out = attn @ vt^T (equal-K quads)
//
// R17 change (single variable): fragment-prefetch loop. Per phase t:
//   stage(t+2) -> VMC(counted: tile t+1 landed, t+2 in flight)
//   BAR_pub    -> all waves' t+1 slices visible
//   ds_read tile t+1 into ALTERNATE reg set; lgkmcnt(8) retires only the
//   OLDER 8 reads (tile t's, FIFO) -> MFMA(t) runs while t+1's reads fly.
//   BAR_done   -> cross-wave: tile t-1's ds_reads (retired by this phase's
//   lgkm upstream) are done before any wave's next stage overwrites that
//   ring slot (stage(t+2) hits buf[(t-1)%3]).
//   Loop unrolled x2 with named reg sets P/Q (rule #20); nt even in all
//   modes (PV Kend is a multiple of 128). The ~150cy exposed ds_read
//   latency — the one untouched chain term across R8-R16 — moves under
//   the previous tile's MFMA.

typedef __attribute__((ext_vector_type(8))) short bf16x8;
typedef __attribute__((ext_vector_type(4))) float f32x4;

#define GLOAD_LDS16(g, l)                                                     \
    __builtin_amdgcn_global_load_lds(                                         \
        (const __attribute__((address_space(1))) void*)(g),                   \
        (__attribute__((address_space(3))) void*)(l), 16, 0, 0)

__device__ __forceinline__ short f2bf(float f) {
    union { float f; unsigned u; } v; v.f = f;
    unsigned r = v.u + 0x7FFFu + ((v.u >> 16) & 1u);
    return (short)(r >> 16);
}
__device__ __forceinline__ float bf2f(short h) {
    union { unsigned u; float f; } v;
    v.u = ((unsigned)(unsigned short)h) << 16;
    return v.f;
}

// ------- fused f32->bf16 converts ----------------------------------------
__global__ __launch_bounds__(256) void convall(
    const float* __restrict__ x, const float* __restrict__ wq,
    const float* __restrict__ wk, short* __restrict__ xb,
    short* __restrict__ wqb, short* __restrict__ wkb) {
    int i = blockIdx.x * 256 + threadIdx.x;  // grid 2048
#pragma unroll
    for (int s = 0; s < 5; ++s) {
        int v = i + s * 524288;              // < 2621440
        const float* src;
        short* dst;
        int off;
        if (v < 2097152)      { src = x;  dst = xb;  off = v; }
        else if (v < 2359296) { src = wq; dst = wqb; off = v - 2097152; }
        else                  { src = wk; dst = wkb; off = v - 2359296; }
        float4 w = ((const float4*)src)[off];
        short4 o;
        o.x = f2bf(w.x); o.y = f2bf(w.y); o.z = f2bf(w.z); o.w = f2bf(w.w);
        ((short4*)dst)[off] = o;
    }
}

// ---------------- wv: f32 [k][n] -> bf16 [n][k] ----------------
__global__ __launch_bounds__(256) void wtrans(const float* __restrict__ W,
                                              short* __restrict__ O) {
    int n0 = blockIdx.x * 64, k0 = blockIdx.y * 64;
    __shared__ float tile[64][65];
    int t = threadIdx.x;
#pragma unroll
    for (int i = 0; i < 16; ++i) {
        int idx = t + i * 256;
        int r = idx >> 6, c = idx & 63;
        tile[r][c] = W[(size_t)(k0 + r) * 1024 + n0 + c];
    }
    __syncthreads();
#pragma unroll
    for (int i = 0; i < 16; ++i) {
        int idx = t + i * 256;
        int r = idx >> 6, c = idx & 63;
        O[(size_t)(n0 + r) * 1024 + k0 + c] = f2bf(tile[c][r]);
    }
}

// ------- 128x128 NT GEMM, BK=32 ring-3, fragment-prefetch -------
// MODE 5: plain bf16 out (ld 1024)
// MODE 1: merged, grid 1056: bid<544 scores (triangular, causal, bf16 out
//         ld 2048); bid>=544 VT (bf16 out [4][1024][2048])
template <int MODE>
__global__ __launch_bounds__(256, 3) void gemm128(
    const short* __restrict__ A0, int lda0, long long sA,
    const short* __restrict__ B0, int ldb0, long long sB,
    void* __restrict__ C0, float scale,
    const short* __restrict__ Av, const short* __restrict__ Bv,
    short* __restrict__ Cv) {

    int m0, n0, z = 0, lda = lda0, ldb = ldb0;
    const short* Ab;
    const short* Bb;
    bool isVT = false;

    {
        // T1: XCD swizzle (grids are multiples of 8)
        const int nblk = gridDim.x;
        const int raw = blockIdx.x;
        int bid = (raw & 7) * (nblk >> 3) + (raw >> 3);
        if (MODE == 5) {
            m0 = (bid >> 3) * 128;
            n0 = (bid & 7) * 128;
            Ab = A0; Bb = B0;
        } else {  // MODE 1
            if (bid < 544) {
                z = bid / 136;
                int f = bid - z * 136;
                int mt = (int)((sqrtf(8.f * f + 1.f) - 1.f) * 0.5f);
                if (mt * (mt + 1) / 2 > f) --mt;
                if ((mt + 1) * (mt + 2) / 2 <= f) ++mt;
                int nt_ = f - mt * (mt + 1) / 2;   // nt_ <= mt (live)
                m0 = mt * 128; n0 = nt_ * 128;
                Ab = A0 + (size_t)z * sA;
                Bb = B0 + (size_t)z * sB;
            } else {
                isVT = true;
                int v = bid - 544;            // 0..511
                m0 = (v >> 6) * 128;          // M=1024
                n0 = (v & 63) * 128;          // N=8192
                Ab = Av; Bb = Bv; lda = 1024; ldb = 1024;
            }
        }
    }

    const int tid = threadIdx.x;
    const int lane = tid & 63;
    const int wid = tid >> 6;
    const int wm = wid >> 1, wn = wid & 1;  // 2x2 waves, wave tile 64x64

    __shared__ __align__(16) short As[3][4096];
    __shared__ __align__(16) short Bs[3][4096];

    f32x4 acc[4][4] = {};

    const int nt = 32;   // K=1024, BK=32 (even)

    const int srow = tid >> 2;                  // 0..63
    const int sl = (tid & 3) ^ ((tid >> 3) & 3);
    const short* Agp = Ab + (size_t)(m0 + srow) * lda + sl * 8;
    const short* Bgp = Bb + (size_t)(n0 + srow) * ldb + sl * 8;

#define SA(kt, bf)                                                            \
    do {                                                                      \
        const int _k = (kt) << 5;                                             \
        GLOAD_LDS16(Agp + _k,                    &As[bf][tid * 8]);           \
        GLOAD_LDS16(Agp + _k + (size_t)64 * lda, &As[bf][2048 + tid * 8]);    \
    } while (0)
#define SB(kt, bf)                                                            \
    do {                                                                      \
        const int _k = (kt) << 5;                                             \
        GLOAD_LDS16(Bgp + _k,                    &Bs[bf][tid * 8]);           \
        GLOAD_LDS16(Bgp + _k + (size_t)64 * ldb, &Bs[bf][2048 + tid * 8]);    \
    } while (0)

    const int r = lane & 15;
    const int g = lane >> 4;

#define LDA4(dst, bf)                                                         \
    _Pragma("unroll") for (int q_ = 0; q_ < 4; ++q_) {                        \
        const int rr = wm * 64 + q_ * 16 + r;                                 \
        dst[q_] = *(const bf16x8*)&As[bf][rr * 32 +                           \
                                          ((g ^ ((rr >> 1) & 3))) * 8];       \
    }
#define LDB4(dst, bf)                                                         \
    _Pragma("unroll") for (int q_ = 0; q_ < 4; ++q_) {                        \
        const int rb = wn * 64 + q_ * 16 + r;                                 \
        dst[q_] = *(const bf16x8*)&Bs[bf][rb * 32 +                           \
                                          ((g ^ ((rb >> 1) & 3))) * 8];       \
    }
#define LGKM(n)                                                               \
    asm volatile("s_waitcnt lgkmcnt(" #n ")" ::: "memory");                   \
    __builtin_amdgcn_sched_barrier(0)
#define VMC(n) asm volatile("s_waitcnt vmcnt(" #n ")" ::: "memory")
#define BAR() __builtin_amdgcn_s_barrier()
#define MF(ar, br)                                                            \
    _Pragma("unroll") for (int mi = 0; mi < 4; ++mi)                          \
        _Pragma("unroll") for (int ni = 0; ni < 4; ++ni)                      \
            acc[mi][ni] = __builtin_amdgcn_mfma_f32_16x16x32_bf16(            \
                ar[mi], br[ni], acc[mi][ni], 0, 0, 0);
#define SUCC(v) ((v) == 2 ? 0 : (v) + 1)

    // prologue: stage tiles 0,1; publish 0; prefetch tile 0 fragments
    SA(0, 0); SB(0, 0);
    SA(1, 1); SB(1, 1);
    VMC(4);              // tile 0 landed (tile 1's 4 in flight)
    BAR();
    bf16x8 aP[4], bP[4], aQ[4], bQ[4];
    LDA4(aP, 0); LDB4(bP, 0);   // tile 0 reads in flight (8)

    int bf = 0, bs = 2;
    for (int t = 0; t < nt; t += 2) {
        // phase A: compute t (P); prefetch t+1 (Q). t+1 always < nt.
        int b1 = SUCC(bf);
        if (t + 2 < nt) { SA(t + 2, bs); SB(t + 2, bs); bs = SUCC(bs); VMC(4); }
        else VMC(0);     // only t+1's 4 outstanding
        BAR();           // publish t+1
        LDA4(aQ, b1); LDB4(bQ, b1);
        LGKM(8);         // retire tile t's 8 reads; t+1's 8 stay in flight
        MF(aP, bP);
        BAR();           // t-1's readers done before next stage reuses slot
        bf = b1;
        // phase B: compute t+1 (Q); prefetch t+2 (P) if it exists.
        b1 = SUCC(bf);
        if (t + 3 < nt) { SA(t + 3, bs); SB(t + 3, bs); bs = SUCC(bs); VMC(4); }
        else if (t + 2 < nt) VMC(0);
        BAR();
        if (t + 2 < nt) {
            LDA4(aP, b1); LDB4(bP, b1);
            LGKM(8);
        } else {
            LGKM(0);     // drain tile t+1's reads before final MFMA
        }
        MF(aQ, bQ);
        BAR();
        bf = b1;
    }

    const int r4 = (lane >> 4) * 4;
#pragma unroll
    for (int mi = 0; mi < 4; ++mi) {
#pragma unroll
        for (int ni = 0; ni < 4; ++ni) {
            int col = n0 + wn * 64 + ni * 16 + r;
#pragma unroll
            for (int i = 0; i < 4; ++i) {
                int rr = m0 + wm * 64 + mi * 16 + r4 + i;
                float v = acc[mi][ni][i];
                if (MODE == 5) {
                    ((short*)C0)[(size_t)rr * 1024 + col] = f2bf(v * scale);
                } else {
                    if (isVT) {
                        Cv[(size_t)(col >> 11) * 2097152 +
                           (size_t)rr * 2048 + (col & 2047)] = f2bf(v);
                    } else if (col <= rr) {
                        ((short*)C0)[(size_t)z * 4194304 +
                                     (size_t)rr * 2048 + col] = f2bf(v);
                    }
                }
            }
        }
    }
#undef SA
#undef SB
#undef LDA4
#undef LDB4
#undef LGKM
#undef VMC
#undef BAR
#undef MF
#undef SUCC
}

// ------- 64x128 NT GEMM, 2 waves, BK=32 ring-3, fragment-prefetch -------
// MODE 0: Mt (bf16 out ld 1024, *scale), grid 128, XCD swizzle
// MODE 2: PV (f32 out), grid 1024, equal-K quads, Kend=((m0+63)|127)+1
template <int MODE>
__global__ __launch_bounds__(128, 2) void gemm64(
    const short* __restrict__ A0, int lda, long long sA,
    const short* __restrict__ B0, int ldb, long long sB,
    void* __restrict__ C0, float scale) {

    int m0, n0, z = 0;
    const short* Ab;
    const short* Bb;

    if (MODE == 2) {
        int i = blockIdx.x;            // 0..1023
        int j = i & 255;
        int mt = j >> 3;               // 0..31
        z = (j >> 1) & 3;
        m0 = mt * 64;
        n0 = ((j & 1) + (i >> 8) * 2) * 128;
        Ab = A0 + (size_t)z * sA;
        Bb = B0 + (size_t)z * sB;
    } else {
        const int nblk = gridDim.x;    // 128
        const int raw = blockIdx.x;
        int bid = (raw & 7) * (nblk >> 3) + (raw >> 3);
        m0 = (bid >> 3) * 64;
        n0 = (bid & 7) * 128;
        Ab = A0; Bb = B0;
    }

    const int tid = threadIdx.x;       // 0..127
    const int lane = tid & 63;
    const int wn = tid >> 6;

    __shared__ __align__(16) short As[3][2048];
    __shared__ __align__(16) short Bs[3][4096];

    f32x4 acc[4][4] = {};

    const int Kend = (MODE == 2) ? (((m0 + 63) | 127) + 1) : 1024;
    const int nt = Kend >> 5;          // multiple of 4 (PV), 32 (Mt): even

    const int srow = tid >> 2;                  // 0..31
    const int sl = (tid & 3) ^ ((tid >> 3) & 3);
    const short* Agp = Ab + (size_t)(m0 + srow) * lda + sl * 8;
    const short* Bgp = Bb + (size_t)(n0 + srow) * ldb + sl * 8;

#define SA6(kt, bf)                                                           \
    do {                                                                      \
        const int _k = (kt) << 5;                                             \
        GLOAD_LDS16(Agp + _k,                    &As[bf][tid * 8]);           \
        GLOAD_LDS16(Agp + _k + (size_t)32 * lda, &As[bf][1024 + tid * 8]);    \
    } while (0)
#define SB6(kt, bf)                                                           \
    do {                                                                      \
        const int _k = (kt) << 5;                                             \
        GLOAD_LDS16(Bgp + _k,                    &Bs[bf][tid * 8]);           \
        GLOAD_LDS16(Bgp + _k + (size_t)32 * ldb, &Bs[bf][1024 + tid * 8]);    \
        GLOAD_LDS16(Bgp + _k + (size_t)64 * ldb, &Bs[bf][2048 + tid * 8]);    \
        GLOAD_LDS16(Bgp + _k + (size_t)96 * ldb, &Bs[bf][3072 + tid * 8]);    \
    } while (0)

    const int r = lane & 15;
    const int g = lane >> 4;

#define LDA4g(dst, bf)                                                        \
    _Pragma("unroll") for (int q_ = 0; q_ < 4; ++q_) {                        \
        const int rr = q_ * 16 + r;                                           \
        dst[q_] = *(const bf16x8*)&As[bf][rr * 32 +                           \
                                          ((g ^ ((rr >> 1) & 3))) * 8];       \
    }
#define LDB4g(dst, bf)                                                        \
    _Pragma("unroll") for (int q_ = 0; q_ < 4; ++q_) {                        \
        const int rb = wn * 64 + q_ * 16 + r;                                 \
        dst[q_] = *(const bf16x8*)&Bs[bf][rb * 32 +                           \
                                          ((g ^ ((rb >> 1) & 3))) * 8];       \
    }
#define LGKM(n)                                                               \
    asm volatile("s_waitcnt lgkmcnt(" #n ")" ::: "memory");                   \
    __builtin_amdgcn_sched_barrier(0)
#define VMC(n) asm volatile("s_waitcnt vmcnt(" #n ")" ::: "memory")
#define BAR() __builtin_amdgcn_s_barrier()
#define MF(ar, br)                                                            \
    _Pragma("unroll") for (int mi = 0; mi < 4; ++mi)                          \
        _Pragma("unroll") for (int ni = 0; ni < 4; ++ni)                      \
            acc[mi][ni] = __builtin_amdgcn_mfma_f32_16x16x32_bf16(            \
                ar[mi], br[ni], acc[mi][ni], 0, 0, 0);
#define SUCC(v) ((v) == 2 ? 0 : (v) + 1)

    SA6(0, 0); SB6(0, 0);
    SA6(1, 1); SB6(1, 1);
    VMC(6);              // tile 0 landed (tile 1's 6 in flight)
    BAR();
    bf16x8 aP[4], bP[4], aQ[4], bQ[4];
    LDA4g(aP, 0); LDB4g(bP, 0);

    int bf = 0, bs = 2;
    for (int t = 0; t < nt; t += 2) {
        // phase A: compute t (P); prefetch t+1 (Q)
        int b1 = SUCC(bf);
        if (t + 2 < nt) { SA6(t + 2, bs); SB6(t + 2, bs); bs = SUCC(bs); VMC(6); }
        else VMC(0);
        BAR();
        LDA4g(aQ, b1); LDB4g(bQ, b1);
        LGKM(8);
        MF(aP, bP);
        BAR();
        bf = b1;
        // phase B: compute t+1 (Q); prefetch t+2 (P) if it exists
        b1 = SUCC(bf);
        if (t + 3 < nt) { SA6(t + 3, bs); SB6(t + 3, bs); bs = SUCC(bs); VMC(6); }
        else if (t + 2 < nt) VMC(0);
        BAR();
        if (t + 2 < nt) {
            LDA4g(aP, b1); LDB4g(bP, b1);
            LGKM(8);
        } else {
            LGKM(0);
        }
        MF(aQ, bQ);
        BAR();
        bf = b1;
    }

    const int r4 = (lane >> 4) * 4;
#pragma unroll
    for (int mi = 0; mi < 4; ++mi) {
#pragma unroll
        for (int ni = 0; ni < 4; ++ni) {
            int col = n0 + wn * 64 + ni * 16 + r;
#pragma unroll
            for (int i = 0; i < 4; ++i) {
                int rr = m0 + mi * 16 + r4 + i;
                float v = acc[mi][ni][i];
                if (MODE == 0) {
                    ((short*)C0)[(size_t)rr * 1024 + col] = f2bf(v * scale);
                } else {
                    ((float*)C0)[(size_t)z * 2097152 +
                                 (size_t)rr * 1024 + col] = v;
                }
            }
        }
    }
#undef SA6
#undef SB6
#undef LDA4g
#undef LDB4g
#undef LGKM
#undef VMC
#undef BAR
#undef MF
#undef SUCC
}

// ------- causal softmax, row per wave, all-register, bf16 in/out -----------
__global__ __launch_bounds__(256) void softmax_wave(short* __restrict__ scores) {
    int row = (blockIdx.x << 2) + (threadIdx.x >> 6);  // 0..8191
    int lane = threadIdx.x & 63;
    int b = row >> 11, i = row & 2047;
    short* srow = scores + ((size_t)(b << 11) + i) * 2048;
    int L = i + 1;
    int Lpad = (i | 127) + 1;

    float vals[32];
    float mx = -1e30f;
#pragma unroll
    for (int s = 0; s < 4; ++s) {
        if (s * 512 < Lpad) {
            int j0 = (s << 9) + (lane << 3);
            bf16x8 h = *(const bf16x8*)&srow[j0];
#pragma unroll
            for (int e = 0; e < 8; ++e) {
                float f = ((j0 + e) < L) ? bf2f(h[e]) : -1e30f;
                vals[s * 8 + e] = f;
                mx = fmaxf(mx, f);
            }
        }
    }
#pragma unroll
    for (int o = 32; o > 0; o >>= 1) mx = fmaxf(mx, __shfl_down(mx, o));
    mx = __shfl(mx, 0);

    float sum = 0.f;
#pragma unroll
    for (int s = 0; s < 4; ++s) {
        if (s * 512 < Lpad) {
#pragma unroll
            for (int e = 0; e < 8; ++e) {
                float ex = __expf(vals[s * 8 + e] - mx);
                vals[s * 8 + e] = ex;
                sum += ex;
            }
        }
    }
#pragma unroll
    for (int o = 32; o > 0; o >>= 1) sum += __shfl_down(sum, o);
    sum = __shfl(sum, 0);
    float rinv = 1.0f / sum;

#pragma unroll
    for (int s = 0; s < 4; ++s) {
        if (s * 512 < Lpad) {
            int j0 = (s << 9) + (lane << 3);
            bf16x8 o8;
#pragma unroll
            for (int e = 0; e < 8; ++e) o8[e] = f2bf(vals[s * 8 + e] * rinv);
            *(bf16x8*)&srow[j0] = o8;
        }
    }
}

extern "C" void kernel_launch(void* const* d_in, const int* in_sizes, int n_in,
                              void* d_out, int out_size, void* d_ws, size_t ws_size,
                              hipStream_t stream) {
    const float* x  = (const float*)d_in[0];
    const float* wq = (const float*)d_in[1];
    const float* wk = (const float*)d_in[2];
    const float* wv = (const float*)d_in[3];
    float* out = (float*)d_out;

    // workspace layout (shorts)
    short* ws16 = (short*)d_ws;
    short* xb  = ws16;                 //  8,388,608
    short* wqb = xb + 8388608;         //  1,048,576
    short* wkb = wqb + 1048576;        //  1,048,576
    short* wtv = wkb + 1048576;        //  1,048,576  Wv^T [n][k]
    short* Mt  = wtv + 1048576;        //  1,048,576  (Wk Wq^T)/32
    short* tb  = Mt + 1048576;         //  8,388,608  t = x M
    short* vt  = tb + 8388608;         //  8,388,608  V^T [4][1024][2048]
    short* scores = vt + 8388608;      // 16,777,216  bf16 [4][2048][2048]

    convall<<<2048, 256, 0, stream>>>(x, wq, wk, xb, wqb, wkb);
    wtrans<<<dim3(16, 16, 1), 256, 0, stream>>>(wv, wtv);
    // Mt[m][n] = sum_e Wk[m][e] Wq[n][e] / 32
    gemm64<0><<<128, 128, 0, stream>>>(
        wkb, 1024, 0LL, wqb, 1024, 0LL, Mt, 0.03125f);
    // t[i][n] = sum_k x[i][k] Mt[n][k]
    gemm128<5><<<512, 256, 0, stream>>>(
        xb, 1024, 0LL, Mt, 1024, 0LL, tb, 1.0f,
        nullptr, nullptr, nullptr);
    // merged: scores (544 live triangular, bf16 out) + VT (512)
    gemm128<1><<<1056, 256, 0, stream>>>(
        tb, 1024, 2097152LL, xb, 1024, 2097152LL, scores, 1.0f,
        wtv, xb, vt);
    softmax_wave<<<2048, 256, 0, stream>>>(scores);
    // out = attn @ vt^T  (gemm64 ring-3, 1024 blocks, equal-K quads)
    gemm64<2><<<1024, 128, 0, stream>>>(
        scores, 2048, 4194304LL, vt, 2048, 2097152LL, out, 1.0f);
}

// Round 18
// 166.686 us; speedup vs baseline: 1.1557x; 1.0419x over previous
//
#include <hip/hip_runtime.h>
#include <hip/hip_bf16.h>

// B=4, S=2048, D=1024. x:[4,2048,1024] f32; wq/wk/wv:[1024,1024] f32.
// out:[4,2048,1024] f32.
//
// R18 = consolidation of best-measured components (no new schedule):
//   scores = x (Wq Wk^T/32) x^T  (Mt precomputed; K-proj eliminated)
//   1. convall: x,wq,wk -> bf16 AND wv -> wtv (transpose) fused: grid
//      2304 = 2048 conv blocks + 256 transpose blocks (one launch saved)
//   2. gemm64<0>:  Mt = (wkb @ wqb^T)/32      [1024x1024] bf16 (R14 core)
//   3. gemm128<5>: t  = xb @ Mt^T             [8192x1024] bf16 (R11 core)
//   4. gemm128<1>: MERGED: 544 live-triangular scores (bf16) + 512 VT
//   5. softmax_wave: row-per-wave register softmax, bf16 in-place
//   6. gemm64<2>:  out = attn @ vt^T (equal-K quads, R14 core)
//
// Component provenance (measured): gemm128 ring-3 BK=32 + counted vmcnt
// (8/4/0) + lgkm0 pin + 0-conflict both-sides XOR swizzle = merged
// 60.1-60.9 us (R11/R13/R14); gemm64 ring-3 PV equal-K quads, 4 blk/CU
// (R14). Session conclusion baked in: this structure's throughput is
// ~575 TF at K=1024, invariant to occupancy/staging-depth/barrier-count/
// chain-density/fragment-prefetch (R8-R17 single-variable experiments).

typedef __attribute__((ext_vector_type(8))) short bf16x8;
typedef __attribute__((ext_vector_type(4))) float f32x4;

#define GLOAD_LDS16(g, l)                                                     \
    __builtin_amdgcn_global_load_lds(                                         \
        (const __attribute__((address_space(1))) void*)(g),                   \
        (__attribute__((address_space(3))) void*)(l), 16, 0, 0)

__device__ __forceinline__ short f2bf(float f) {
    union { float f; unsigned u; } v; v.f = f;
    unsigned r = v.u + 0x7FFFu + ((v.u >> 16) & 1u);
    return (short)(r >> 16);
}
__device__ __forceinline__ float bf2f(short h) {
    union { unsigned u; float f; } v;
    v.u = ((unsigned)(unsigned short)h) << 16;
    return v.f;
}

// ------- fused converts + wv transpose ------------------------------------
// bid < 2048: grid-stride f32->bf16 for x (2M f4), wq, wk (256K f4 each)
// bid >= 2048 (256 blocks): wv f32 [k][n] -> wtv bf16 [n][k], 64x64 tiles
__global__ __launch_bounds__(256) void convall(
    const float* __restrict__ x, const float* __restrict__ wq,
    const float* __restrict__ wk, const float* __restrict__ wv,
    short* __restrict__ xb, short* __restrict__ wqb,
    short* __restrict__ wkb, short* __restrict__ wtv) {
    __shared__ float tile[64][65];
    int bid = blockIdx.x;
    int t = threadIdx.x;
    if (bid < 2048) {
        int i = bid * 256 + t;
#pragma unroll
        for (int s = 0; s < 5; ++s) {
            int v = i + s * 524288;              // < 2621440
            const float* src;
            short* dst;
            int off;
            if (v < 2097152)      { src = x;  dst = xb;  off = v; }
            else if (v < 2359296) { src = wq; dst = wqb; off = v - 2097152; }
            else                  { src = wk; dst = wkb; off = v - 2359296; }
            float4 w = ((const float4*)src)[off];
            short4 o;
            o.x = f2bf(w.x); o.y = f2bf(w.y); o.z = f2bf(w.z); o.w = f2bf(w.w);
            ((short4*)dst)[off] = o;
        }
    } else {
        int b2 = bid - 2048;                      // 0..255
        int n0 = (b2 & 15) * 64, k0 = (b2 >> 4) * 64;
#pragma unroll
        for (int i = 0; i < 16; ++i) {
            int idx = t + i * 256;
            int r = idx >> 6, c = idx & 63;
            tile[r][c] = wv[(size_t)(k0 + r) * 1024 + n0 + c];
        }
        __syncthreads();
#pragma unroll
        for (int i = 0; i < 16; ++i) {
            int idx = t + i * 256;
            int r = idx >> 6, c = idx & 63;
            wtv[(size_t)(n0 + r) * 1024 + k0 + c] = f2bf(tile[c][r]);
        }
    }
}

// ------- 128x128 NT GEMM, BK=32, 3-buffer ring, counted vmcnt (R11) -------
// MODE 5: plain bf16 out (ld 1024), *scale
// MODE 1: merged, grid 1056: bid<544 scores (triangular, causal, bf16 out
//         ld 2048); bid>=544 VT (bf16 out [4][1024][2048])
template <int MODE>
__global__ __launch_bounds__(256, 3) void gemm128(
    const short* __restrict__ A0, int lda0, long long sA,
    const short* __restrict__ B0, int ldb0, long long sB,
    void* __restrict__ C0, float scale,
    const short* __restrict__ Av, const short* __restrict__ Bv,
    short* __restrict__ Cv) {

    int m0, n0, z = 0, lda = lda0, ldb = ldb0;
    const short* Ab;
    const short* Bb;
    bool isVT = false;

    {
        // T1: XCD swizzle (grids are multiples of 8)
        const int nblk = gridDim.x;
        const int raw = blockIdx.x;
        int bid = (raw & 7) * (nblk >> 3) + (raw >> 3);
        if (MODE == 5) {
            m0 = (bid >> 3) * 128;
            n0 = (bid & 7) * 128;
            Ab = A0; Bb = B0;
        } else {  // MODE 1
            if (bid < 544) {
                z = bid / 136;
                int f = bid - z * 136;
                int mt = (int)((sqrtf(8.f * f + 1.f) - 1.f) * 0.5f);
                if (mt * (mt + 1) / 2 > f) --mt;
                if ((mt + 1) * (mt + 2) / 2 <= f) ++mt;
                int nt_ = f - mt * (mt + 1) / 2;   // nt_ <= mt (live)
                m0 = mt * 128; n0 = nt_ * 128;
                Ab = A0 + (size_t)z * sA;
                Bb = B0 + (size_t)z * sB;
            } else {
                isVT = true;
                int v = bid - 544;            // 0..511
                m0 = (v >> 6) * 128;          // M=1024
                n0 = (v & 63) * 128;          // N=8192
                Ab = Av; Bb = Bv; lda = 1024; ldb = 1024;
            }
        }
    }

    const int tid = threadIdx.x;
    const int lane = tid & 63;
    const int wid = tid >> 6;
    const int wm = wid >> 1, wn = wid & 1;  // 2x2 waves, wave tile 64x64

    __shared__ __align__(16) short As[3][4096];
    __shared__ __align__(16) short Bs[3][4096];

    f32x4 acc[4][4] = {};

    const int nt = 32;   // K=1024, BK=32

    const int srow = tid >> 2;                  // 0..63
    const int sl = (tid & 3) ^ ((tid >> 3) & 3);
    const short* Agp = Ab + (size_t)(m0 + srow) * lda + sl * 8;
    const short* Bgp = Bb + (size_t)(n0 + srow) * ldb + sl * 8;

#define SA(kt, bf)                                                            \
    do {                                                                      \
        const int _k = (kt) << 5;                                             \
        GLOAD_LDS16(Agp + _k,                    &As[bf][tid * 8]);           \
        GLOAD_LDS16(Agp + _k + (size_t)64 * lda, &As[bf][2048 + tid * 8]);    \
    } while (0)
#define SB(kt, bf)                                                            \
    do {                                                                      \
        const int _k = (kt) << 5;                                             \
        GLOAD_LDS16(Bgp + _k,                    &Bs[bf][tid * 8]);           \
        GLOAD_LDS16(Bgp + _k + (size_t)64 * ldb, &Bs[bf][2048 + tid * 8]);    \
    } while (0)

    const int r = lane & 15;
    const int g = lane >> 4;   // logical 16B slot (k-chunk) 0..3

#define LDA4(dst, bf)                                                         \
    _Pragma("unroll") for (int q_ = 0; q_ < 4; ++q_) {                        \
        const int rr = wm * 64 + q_ * 16 + r;                                 \
        dst[q_] = *(const bf16x8*)&As[bf][rr * 32 +                           \
                                          ((g ^ ((rr >> 1) & 3))) * 8];       \
    }
#define LDB4(dst, bf)                                                         \
    _Pragma("unroll") for (int q_ = 0; q_ < 4; ++q_) {                        \
        const int rb = wn * 64 + q_ * 16 + r;                                 \
        dst[q_] = *(const bf16x8*)&Bs[bf][rb * 32 +                           \
                                          ((g ^ ((rb >> 1) & 3))) * 8];       \
    }
#define LGKM0()                                                               \
    asm volatile("s_waitcnt lgkmcnt(0)" ::: "memory");                        \
    __builtin_amdgcn_sched_barrier(0)
#define VMC(n) asm volatile("s_waitcnt vmcnt(" #n ")" ::: "memory")
#define BAR() __builtin_amdgcn_s_barrier()
#define MF(ar, br)                                                            \
    _Pragma("unroll") for (int mi = 0; mi < 4; ++mi)                          \
        _Pragma("unroll") for (int ni = 0; ni < 4; ++ni)                      \
            acc[mi][ni] = __builtin_amdgcn_mfma_f32_16x16x32_bf16(            \
                ar[mi], br[ni], acc[mi][ni], 0, 0, 0);

    SA(0, 0); SB(0, 0);
    SA(1, 1); SB(1, 1);

    int bf = 0;   // buffer holding tile t
    int bs = 2;   // buffer to stage tile t+2 into
    for (int t = 0; t < nt; ++t) {
        bf16x8 a[4], b[4];
        if (t + 2 < nt) {
            SA(t + 2, bs); SB(t + 2, bs);
            VMC(8);   // wait tile t only; t+1,t+2 stay in flight
        } else if (t + 1 < nt) {
            VMC(4);
        } else {
            VMC(0);
        }
        BAR();   // tile t visible to all waves; prior reads (t-1) retired
        LDA4(a, bf); LDB4(b, bf);
        LGKM0();
        MF(a, b);
        BAR();   // all waves done reading buf bf before it is restaged
        bf = (bf == 2) ? 0 : bf + 1;
        bs = (bs == 2) ? 0 : bs + 1;
    }

    const int r4 = (lane >> 4) * 4;
#pragma unroll
    for (int mi = 0; mi < 4; ++mi) {
#pragma unroll
        for (int ni = 0; ni < 4; ++ni) {
            int col = n0 + wn * 64 + ni * 16 + r;
#pragma unroll
            for (int i = 0; i < 4; ++i) {
                int rr = m0 + wm * 64 + mi * 16 + r4 + i;
                float v = acc[mi][ni][i];
                if (MODE == 5) {
                    ((short*)C0)[(size_t)rr * 1024 + col] = f2bf(v * scale);
                } else {
                    if (isVT) {
                        Cv[(size_t)(col >> 11) * 2097152 +
                           (size_t)rr * 2048 + (col & 2047)] = f2bf(v);
                    } else if (col <= rr) {
                        ((short*)C0)[(size_t)z * 4194304 +
                                     (size_t)rr * 2048 + col] = f2bf(v);
                    }
                }
            }
        }
    }
#undef SA
#undef SB
#undef LDA4
#undef LDB4
#undef LGKM0
#undef VMC
#undef BAR
#undef MF
}

// ------- 64x128 NT GEMM, 2 waves, BK=32 3-ring (R14, proven) -------
// MODE 0: Mt (bf16 out ld 1024, *scale), grid 128, XCD swizzle
// MODE 2: PV (f32 out), grid 1024, equal-K quads, Kend=((m0+63)|127)+1
template <int MODE>
__global__ __launch_bounds__(128, 2) void gemm64(
    const short* __restrict__ A0, int lda, long long sA,
    const short* __restrict__ B0, int ldb, long long sB,
    void* __restrict__ C0, float scale) {

    int m0, n0, z = 0;
    const short* Ab;
    const short* Bb;

    if (MODE == 2) {
        // co-resident quads (i, i+256, i+512, i+768) share (mt, z):
        // equal K, shared attn A-panel; n differs.
        int i = blockIdx.x;            // 0..1023
        int j = i & 255;
        int mt = j >> 3;               // 0..31
        z = (j >> 1) & 3;
        m0 = mt * 64;
        n0 = ((j & 1) + (i >> 8) * 2) * 128;
        Ab = A0 + (size_t)z * sA;
        Bb = B0 + (size_t)z * sB;
    } else {
        const int nblk = gridDim.x;    // 128
        const int raw = blockIdx.x;
        int bid = (raw & 7) * (nblk >> 3) + (raw >> 3);
        m0 = (bid >> 3) * 64;
        n0 = (bid & 7) * 128;
        Ab = A0; Bb = B0;
    }

    const int tid = threadIdx.x;       // 0..127
    const int lane = tid & 63;
    const int wn = tid >> 6;

    __shared__ __align__(16) short As[3][2048];
    __shared__ __align__(16) short Bs[3][4096];

    f32x4 acc[4][4] = {};

    const int Kend = (MODE == 2) ? (((m0 + 63) | 127) + 1) : 1024;
    const int nt = Kend >> 5;

    const int srow = tid >> 2;                  // 0..31
    const int sl = (tid & 3) ^ ((tid >> 3) & 3);
    const short* Agp = Ab + (size_t)(m0 + srow) * lda + sl * 8;
    const short* Bgp = Bb + (size_t)(n0 + srow) * ldb + sl * 8;

#define SA6(kt, bf)                                                           \
    do {                                                                      \
        const int _k = (kt) << 5;                                             \
        GLOAD_LDS16(Agp + _k,                    &As[bf][tid * 8]);           \
        GLOAD_LDS16(Agp + _k + (size_t)32 * lda, &As[bf][1024 + tid * 8]);    \
    } while (0)
#define SB6(kt, bf)                                                           \
    do {                                                                      \
        const int _k = (kt) << 5;                                             \
        GLOAD_LDS16(Bgp + _k,                    &Bs[bf][tid * 8]);           \
        GLOAD_LDS16(Bgp + _k + (size_t)32 * ldb, &Bs[bf][1024 + tid * 8]);    \
        GLOAD_LDS16(Bgp + _k + (size_t)64 * ldb, &Bs[bf][2048 + tid * 8]);    \
        GLOAD_LDS16(Bgp + _k + (size_t)96 * ldb, &Bs[bf][3072 + tid * 8]);    \
    } while (0)

    const int r = lane & 15;
    const int g = lane >> 4;

#define LDA4g(dst, bf)                                                        \
    _Pragma("unroll") for (int q_ = 0; q_ < 4; ++q_) {                        \
        const int rr = q_ * 16 + r;                                           \
        dst[q_] = *(const bf16x8*)&As[bf][rr * 32 +                           \
                                          ((g ^ ((rr >> 1) & 3))) * 8];       \
    }
#define LDB4g(dst, bf)                                                        \
    _Pragma("unroll") for (int q_ = 0; q_ < 4; ++q_) {                        \
        const int rb = wn * 64 + q_ * 16 + r;                                 \
        dst[q_] = *(const bf16x8*)&Bs[bf][rb * 32 +                           \
                                          ((g ^ ((rb >> 1) & 3))) * 8];       \
    }
#define LGKM0()                                                               \
    asm volatile("s_waitcnt lgkmcnt(0)" ::: "memory");                        \
    __builtin_amdgcn_sched_barrier(0)
#define VMC(n) asm volatile("s_waitcnt vmcnt(" #n ")" ::: "memory")
#define BAR() __builtin_amdgcn_s_barrier()
#define MF(ar, br)                                                            \
    _Pragma("unroll") for (int mi = 0; mi < 4; ++mi)                          \
        _Pragma("unroll") for (int ni = 0; ni < 4; ++ni)                      \
            acc[mi][ni] = __builtin_amdgcn_mfma_f32_16x16x32_bf16(            \
                ar[mi], br[ni], acc[mi][ni], 0, 0, 0);

    SA6(0, 0); SB6(0, 0);
    SA6(1, 1); SB6(1, 1);

    int bf = 0;
    int bs = 2;
    for (int t = 0; t < nt; ++t) {
        bf16x8 a[4], b[4];
        if (t + 2 < nt) {
            SA6(t + 2, bs); SB6(t + 2, bs);
            VMC(12);
        } else if (t + 1 < nt) {
            VMC(6);
        } else {
            VMC(0);
        }
        BAR();
        LDA4g(a, bf); LDB4g(b, bf);
        LGKM0();
        MF(a, b);
        BAR();
        bf = (bf == 2) ? 0 : bf + 1;
        bs = (bs == 2) ? 0 : bs + 1;
    }

    const int r4 = (lane >> 4) * 4;
#pragma unroll
    for (int mi = 0; mi < 4; ++mi) {
#pragma unroll
        for (int ni = 0; ni < 4; ++ni) {
            int col = n0 + wn * 64 + ni * 16 + r;
#pragma unroll
            for (int i = 0; i < 4; ++i) {
                int rr = m0 + mi * 16 + r4 + i;
                float v = acc[mi][ni][i];
                if (MODE == 0) {
                    ((short*)C0)[(size_t)rr * 1024 + col] = f2bf(v * scale);
                } else {
                    ((float*)C0)[(size_t)z * 2097152 +
                                 (size_t)rr * 1024 + col] = v;
                }
            }
        }
    }
#undef SA6
#undef SB6
#undef LDA4g
#undef LDB4g
#undef LGKM0
#undef VMC
#undef BAR
#undef MF
}

// ------- causal softmax, row per wave, all-register, bf16 in/out -----------
__global__ __launch_bounds__(256) void softmax_wave(short* __restrict__ scores) {
    int row = (blockIdx.x << 2) + (threadIdx.x >> 6);  // 0..8191
    int lane = threadIdx.x & 63;
    int b = row >> 11, i = row & 2047;
    short* srow = scores + ((size_t)(b << 11) + i) * 2048;
    int L = i + 1;
    int Lpad = (i | 127) + 1;   // PV read extent for this row's block

    float vals[32];
    float mx = -1e30f;
#pragma unroll
    for (int s = 0; s < 4; ++s) {
        if (s * 512 < Lpad) {   // wave-uniform branch
            int j0 = (s << 9) + (lane << 3);
            bf16x8 h = *(const bf16x8*)&srow[j0];
#pragma unroll
            for (int e = 0; e < 8; ++e) {
                float f = ((j0 + e) < L) ? bf2f(h[e]) : -1e30f;
                vals[s * 8 + e] = f;
                mx = fmaxf(mx, f);
            }
        }
    }
#pragma unroll
    for (int o = 32; o > 0; o >>= 1) mx = fmaxf(mx, __shfl_down(mx, o));
    mx = __shfl(mx, 0);

    float sum = 0.f;
#pragma unroll
    for (int s = 0; s < 4; ++s) {
        if (s * 512 < Lpad) {
#pragma unroll
            for (int e = 0; e < 8; ++e) {
                float ex = __expf(vals[s * 8 + e] - mx);  // masked -> 0
                vals[s * 8 + e] = ex;
                sum += ex;
            }
        }
    }
#pragma unroll
    for (int o = 32; o > 0; o >>= 1) sum += __shfl_down(sum, o);
    sum = __shfl(sum, 0);
    float rinv = 1.0f / sum;

#pragma unroll
    for (int s = 0; s < 4; ++s) {
        if (s * 512 < Lpad) {
            int j0 = (s << 9) + (lane << 3);
            bf16x8 o8;
#pragma unroll
            for (int e = 0; e < 8; ++e) o8[e] = f2bf(vals[s * 8 + e] * rinv);
            *(bf16x8*)&srow[j0] = o8;
        }
    }
}

extern "C" void kernel_launch(void* const* d_in, const int* in_sizes, int n_in,
                              void* d_out, int out_size, void* d_ws, size_t ws_size,
                              hipStream_t stream) {
    const float* x  = (const float*)d_in[0];
    const float* wq = (const float*)d_in[1];
    const float* wk = (const float*)d_in[2];
    const float* wv = (const float*)d_in[3];
    float* out = (float*)d_out;

    // workspace layout (shorts)
    short* ws16 = (short*)d_ws;
    short* xb  = ws16;                 //  8,388,608
    short* wqb = xb + 8388608;         //  1,048,576
    short* wkb = wqb + 1048576;        //  1,048,576
    short* wtv = wkb + 1048576;        //  1,048,576  Wv^T [n][k]
    short* Mt  = wtv + 1048576;        //  1,048,576  (Wk Wq^T)/32
    short* tb  = Mt + 1048576;         //  8,388,608  t = x M
    short* vt  = tb + 8388608;         //  8,388,608  V^T [4][1024][2048]
    short* scores = vt + 8388608;      // 16,777,216  bf16 [4][2048][2048]

    // fused converts + wv transpose (2048 + 256 blocks)
    convall<<<2304, 256, 0, stream>>>(x, wq, wk, wv, xb, wqb, wkb, wtv);
    // Mt[m][n] = sum_e Wk[m][e] Wq[n][e] / 32
    gemm64<0><<<128, 128, 0, stream>>>(
        wkb, 1024, 0LL, wqb, 1024, 0LL, Mt, 0.03125f);
    // t[i][n] = sum_k x[i][k] Mt[n][k]
    gemm128<5><<<512, 256, 0, stream>>>(
        xb, 1024, 0LL, Mt, 1024, 0LL, tb, 1.0f,
        nullptr, nullptr, nullptr);
    // merged: scores (544 live triangular, bf16 out) + VT (512)
    gemm128<1><<<1056, 256, 0, stream>>>(
        tb, 1024, 2097152LL, xb, 1024, 2097152LL, scores, 1.0f,
        wtv, xb, vt);
    softmax_wave<<<2048, 256, 0, stream>>>(scores);
    // out = attn @ vt^T  (gemm64 3-ring, 1024 blocks, equal-K quads)
    gemm64<2><<<1024, 128, 0, stream>>>(
        scores, 2048, 4194304LL, vt, 2048, 2097152LL, out, 1.0f);
}